// Round 4
// baseline (637.432 us; speedup 1.0000x reference)
//
#include <hip/hip_runtime.h>
#include <hip/hip_fp16.h>

#define N_NODES 100000
#define N_EDGES 3200000
#define IN_DIM 128
#define HID 64
#define NUM_GRAPHS 512
#define NUM_CLASSES 10

#define BSHIFT 7
#define BUCKET_W 128
#define NBUCKET ((N_NODES + BUCKET_W - 1) / BUCKET_W)  // 782
#define SRC_BITS 17
#define SRC_MASK ((1 << SRC_BITS) - 1)

// ---------------- CSR build (bucketed, no per-edge global atomics) ----------

__global__ __launch_bounds__(256) void bucket_hist_kernel(const int* __restrict__ dst,
                                                          int* __restrict__ bucket_cnt) {
  __shared__ int h[NBUCKET];
  for (int i = threadIdx.x; i < NBUCKET; i += 256) h[i] = 0;
  __syncthreads();
  int chunk = (N_EDGES + gridDim.x - 1) / gridDim.x;
  int e0 = blockIdx.x * chunk, e1 = min(e0 + chunk, N_EDGES);
  for (int e = e0 + threadIdx.x; e < e1; e += 256)
    atomicAdd(&h[dst[e] >> BSHIFT], 1);
  __syncthreads();
  for (int i = threadIdx.x; i < NBUCKET; i += 256)
    if (h[i]) atomicAdd(&bucket_cnt[i], h[i]);
}

__global__ __launch_bounds__(64) void bucket_scan_kernel(const int* __restrict__ bucket_cnt,
                                                         int* __restrict__ bucket_base,
                                                         int* __restrict__ bucket_cursor,
                                                         int* __restrict__ row_ptr) {
  int lane = threadIdx.x;
  int carry = 0;
  for (int base = 0; base < NBUCKET; base += 64) {
    int i = base + lane;
    int v = (i < NBUCKET) ? bucket_cnt[i] : 0;
    int x = v;
#pragma unroll
    for (int off = 1; off < 64; off <<= 1) {
      int t = __shfl_up(x, off);
      if (lane >= off) x += t;
    }
    if (i < NBUCKET) {
      int ex = carry + x - v;
      bucket_base[i] = ex;
      bucket_cursor[i] = ex;
    }
    carry += __shfl(x, 63);
  }
  if (lane == 0) {
    bucket_base[NBUCKET] = carry;
    row_ptr[N_NODES] = carry;  // == N_EDGES
  }
}

// pair = (dst&127)<<17 | src   (src < 2^17)
__global__ __launch_bounds__(256) void pair_scatter_kernel(const int* __restrict__ src,
                                                           const int* __restrict__ dst,
                                                           int* __restrict__ bucket_cursor,
                                                           unsigned* __restrict__ pair_buf) {
  __shared__ int h[NBUCKET];
  for (int i = threadIdx.x; i < NBUCKET; i += 256) h[i] = 0;
  __syncthreads();
  int chunk = (N_EDGES + gridDim.x - 1) / gridDim.x;
  int e0 = blockIdx.x * chunk, e1 = min(e0 + chunk, N_EDGES);
  for (int e = e0 + threadIdx.x; e < e1; e += 256)
    atomicAdd(&h[dst[e] >> BSHIFT], 1);
  __syncthreads();
  for (int i = threadIdx.x; i < NBUCKET; i += 256) {
    int c = h[i];
    if (c) h[i] = atomicAdd(&bucket_cursor[i], c);
  }
  __syncthreads();
  for (int e = e0 + threadIdx.x; e < e1; e += 256) {
    int d = dst[e];
    int pos = atomicAdd(&h[d >> BSHIFT], 1);  // LDS atomic
    pair_buf[pos] = ((unsigned)(d & (BUCKET_W - 1)) << SRC_BITS) | (unsigned)src[e];
  }
}

__global__ __launch_bounds__(256) void bucket_fill_kernel(const unsigned* __restrict__ pair_buf,
                                                          const int* __restrict__ bucket_base,
                                                          int* __restrict__ csr_src,
                                                          int* __restrict__ row_ptr,
                                                          float* __restrict__ dinv) {
  int b = blockIdx.x;
  int n0 = b << BSHIFT;
  int n1 = min(n0 + BUCKET_W, N_NODES);
  int nn = n1 - n0;
  int eb0 = bucket_base[b], eb1 = bucket_base[b + 1];
  __shared__ int hist[BUCKET_W];
  __shared__ int wtot[2];
  int tid = threadIdx.x;
  if (tid < BUCKET_W) hist[tid] = 0;
  __syncthreads();
  for (int e = eb0 + tid; e < eb1; e += 256)
    atomicAdd(&hist[pair_buf[e] >> SRC_BITS], 1);
  __syncthreads();
  int v = 0, x = 0;
  if (tid < BUCKET_W) {
    v = hist[tid];
    x = v;
#pragma unroll
    for (int off = 1; off < 64; off <<= 1) {
      int t = __shfl_up(x, off);
      if ((tid & 63) >= off) x += t;
    }
    if ((tid & 63) == 63) wtot[tid >> 6] = x;
  }
  __syncthreads();
  if (tid < BUCKET_W) {
    int incl = x + ((tid >= 64) ? wtot[0] : 0);
    int base = eb0 + incl - v;  // exclusive
    if (tid < nn) {
      row_ptr[n0 + tid] = base;
      dinv[n0 + tid] = rsqrtf((float)(v + 1));
    }
    hist[tid] = base;  // becomes the cursor
  }
  __syncthreads();
  for (int e = eb0 + tid; e < eb1; e += 256) {
    unsigned p = pair_buf[e];
    int pos = atomicAdd(&hist[p >> SRC_BITS], 1);  // LDS atomic
    csr_src[pos] = (int)(p & SRC_MASK);
  }
}

// ---------------- GEMM: hp[n][64] = fp16( (A[n][K] @ W[K][64]) * dinv[n] ) --
template <int K>
__global__ __launch_bounds__(256) void gemm_kernel(const float* __restrict__ A,
                                                   const float* __restrict__ W,
                                                   const float* __restrict__ dinv,
                                                   __half* __restrict__ hp, int n) {
  __shared__ float As[64][68];
  __shared__ float Ws[64][64];
  int tid = threadIdx.x;
  int row0 = blockIdx.x * 64;
  int tx = tid & 15, ty = tid >> 4;
  float acc[4][4] = {};
  for (int k0 = 0; k0 < K; k0 += 64) {
    for (int idx = tid * 4; idx < 64 * 64; idx += 1024) {
      int r = idx >> 6, c = idx & 63;
      float4 v = make_float4(0.f, 0.f, 0.f, 0.f);
      if (row0 + r < n)
        v = *(const float4*)&A[(size_t)(row0 + r) * K + k0 + c];
      *(float4*)&As[r][c] = v;
    }
    for (int idx = tid * 4; idx < 64 * 64; idx += 1024) {
      int r = idx >> 6, c = idx & 63;
      *(float4*)&Ws[r][c] = *(const float4*)&W[(size_t)(k0 + r) * 64 + c];
    }
    __syncthreads();
#pragma unroll
    for (int k = 0; k < 64; k += 4) {
      float av[4][4], wv[4][4];
#pragma unroll
      for (int i = 0; i < 4; ++i)
        *(float4*)&av[i][0] = *(float4*)&As[ty * 4 + i][k];
#pragma unroll
      for (int kk = 0; kk < 4; ++kk)
        *(float4*)&wv[kk][0] = *(float4*)&Ws[k + kk][tx * 4];
#pragma unroll
      for (int kk = 0; kk < 4; ++kk)
#pragma unroll
        for (int i = 0; i < 4; ++i)
#pragma unroll
          for (int j = 0; j < 4; ++j)
            acc[i][j] += av[i][kk] * wv[kk][j];
    }
    __syncthreads();
  }
#pragma unroll
  for (int i = 0; i < 4; ++i) {
    int row = row0 + ty * 4 + i;
    if (row < n) {
      float di = dinv[row];
      union {
        uint2 u;
        __half2 h[2];
      } pk;
      pk.h[0] = __floats2half2_rn(acc[i][0] * di, acc[i][1] * di);
      pk.h[1] = __floats2half2_rn(acc[i][2] * di, acc[i][3] * di);
      *(uint2*)&hp[(size_t)row * 64 + tx * 4] = pk.u;
    }
  }
}

// ---------------- Aggregate (fp16 gather): wave per node, lane per dim ------
__global__ __launch_bounds__(256) void aggregate_kernel(
    const __half* __restrict__ hp, const int* __restrict__ row_ptr,
    const int* __restrict__ csr_src, const float* __restrict__ dinv,
    const float* __restrict__ bias, float* __restrict__ out, int relu) {
  int node = blockIdx.x * 4 + (threadIdx.x >> 6);
  if (node >= N_NODES) return;
  int lane = threadIdx.x & 63;
  int beg = row_ptr[node], end = row_ptr[node + 1];
  float acc = __half2float(hp[(unsigned)(node * HID + lane)]);  // self loop
  float acc2 = 0.f;
  int e = beg;
  for (; e + 8 <= end; e += 8) {
    int s0 = csr_src[e + 0];
    int s1 = csr_src[e + 1];
    int s2 = csr_src[e + 2];
    int s3 = csr_src[e + 3];
    int s4 = csr_src[e + 4];
    int s5 = csr_src[e + 5];
    int s6 = csr_src[e + 6];
    int s7 = csr_src[e + 7];
    float v0 = __half2float(hp[(unsigned)(s0 * HID + lane)]);
    float v1 = __half2float(hp[(unsigned)(s1 * HID + lane)]);
    float v2 = __half2float(hp[(unsigned)(s2 * HID + lane)]);
    float v3 = __half2float(hp[(unsigned)(s3 * HID + lane)]);
    float v4 = __half2float(hp[(unsigned)(s4 * HID + lane)]);
    float v5 = __half2float(hp[(unsigned)(s5 * HID + lane)]);
    float v6 = __half2float(hp[(unsigned)(s6 * HID + lane)]);
    float v7 = __half2float(hp[(unsigned)(s7 * HID + lane)]);
    acc += v0 + v1 + v2 + v3;
    acc2 += v4 + v5 + v6 + v7;
  }
  for (; e + 2 <= end; e += 2) {
    int s0 = csr_src[e + 0];
    int s1 = csr_src[e + 1];
    acc += __half2float(hp[(unsigned)(s0 * HID + lane)]);
    acc2 += __half2float(hp[(unsigned)(s1 * HID + lane)]);
  }
  if (e < end) acc += __half2float(hp[(unsigned)(csr_src[e] * HID + lane)]);
  acc = (acc + acc2) * dinv[node] + bias[lane];
  if (relu) acc = fmaxf(acc, 0.0f);
  out[(unsigned)(node * HID + lane)] = acc;
}

// ---------------- Aggregate layer-3 fused with mean-pool --------------------
__global__ __launch_bounds__(256) void aggregate_pool_kernel(
    const __half* __restrict__ hp, const int* __restrict__ row_ptr,
    const int* __restrict__ csr_src, const float* __restrict__ dinv,
    const float* __restrict__ bias, const int* __restrict__ batch,
    float* __restrict__ pool, int* __restrict__ cnt) {
  int node = blockIdx.x * 4 + (threadIdx.x >> 6);
  if (node >= N_NODES) return;
  int lane = threadIdx.x & 63;
  int beg = row_ptr[node], end = row_ptr[node + 1];
  float acc = __half2float(hp[(unsigned)(node * HID + lane)]);
  float acc2 = 0.f;
  int e = beg;
  for (; e + 8 <= end; e += 8) {
    int s0 = csr_src[e + 0];
    int s1 = csr_src[e + 1];
    int s2 = csr_src[e + 2];
    int s3 = csr_src[e + 3];
    int s4 = csr_src[e + 4];
    int s5 = csr_src[e + 5];
    int s6 = csr_src[e + 6];
    int s7 = csr_src[e + 7];
    float v0 = __half2float(hp[(unsigned)(s0 * HID + lane)]);
    float v1 = __half2float(hp[(unsigned)(s1 * HID + lane)]);
    float v2 = __half2float(hp[(unsigned)(s2 * HID + lane)]);
    float v3 = __half2float(hp[(unsigned)(s3 * HID + lane)]);
    float v4 = __half2float(hp[(unsigned)(s4 * HID + lane)]);
    float v5 = __half2float(hp[(unsigned)(s5 * HID + lane)]);
    float v6 = __half2float(hp[(unsigned)(s6 * HID + lane)]);
    float v7 = __half2float(hp[(unsigned)(s7 * HID + lane)]);
    acc += v0 + v1 + v2 + v3;
    acc2 += v4 + v5 + v6 + v7;
  }
  for (; e + 2 <= end; e += 2) {
    int s0 = csr_src[e + 0];
    int s1 = csr_src[e + 1];
    acc += __half2float(hp[(unsigned)(s0 * HID + lane)]);
    acc2 += __half2float(hp[(unsigned)(s1 * HID + lane)]);
  }
  if (e < end) acc += __half2float(hp[(unsigned)(csr_src[e] * HID + lane)]);
  acc = (acc + acc2) * dinv[node] + bias[lane];
  int g = batch[node];
  atomicAdd(&pool[(unsigned)(g * HID + lane)], acc);
  if (lane == 0) atomicAdd(&cnt[g], 1);
}

// ---------------- FC ---------------------------------------------------------
__global__ __launch_bounds__(64) void fc_kernel(const float* __restrict__ pool,
                                                const int* __restrict__ cnt,
                                                const float* __restrict__ Wfc,
                                                const float* __restrict__ bfc,
                                                float* __restrict__ out) {
  int g = blockIdx.x;
  int t = threadIdx.x;
  __shared__ float row[64];
  float inv = 1.0f / fmaxf((float)cnt[g], 1.0f);
  row[t] = pool[(size_t)g * HID + t] * inv;
  __syncthreads();
  if (t < NUM_CLASSES) {
    float acc = bfc[t];
#pragma unroll
    for (int k = 0; k < HID; ++k) acc += row[k] * Wfc[k * NUM_CLASSES + t];
    out[(size_t)g * NUM_CLASSES + t] = acc;
  }
}

// ---------------- launch -----------------------------------------------------
extern "C" void kernel_launch(void* const* d_in, const int* in_sizes, int n_in,
                              void* d_out, int out_size, void* d_ws, size_t ws_size,
                              hipStream_t stream) {
  const float* x = (const float*)d_in[0];
  const int* edge_index = (const int*)d_in[1];
  const int* batch = (const int*)d_in[2];
  const float* W1 = (const float*)d_in[3];
  const float* b1 = (const float*)d_in[4];
  const float* W2 = (const float*)d_in[5];
  const float* b2 = (const float*)d_in[6];
  const float* W3 = (const float*)d_in[7];
  const float* b3 = (const float*)d_in[8];
  const float* Wfc = (const float*)d_in[9];
  const float* bfc = (const float*)d_in[10];
  float* out = (float*)d_out;

  const int* src = edge_index;
  const int* dst = edge_index + N_EDGES;

  // workspace layout
  char* w = (char*)d_ws;
  float* hf = (float*)w;                           // N*64 fp32 (aggregate out / GEMM A)
  __half* hp = (__half*)(hf + (size_t)N_NODES * HID);  // N*64 fp16 (gather buf)
  float* dinv = (float*)(hp + (size_t)N_NODES * HID);  // N floats
  int* row_ptr = (int*)(dinv + N_NODES);           // N+1
  int* csr_src = row_ptr + (N_NODES + 1);          // E
  int* bucket_cnt = csr_src + N_EDGES;             // NBUCKET
  int* bucket_base = bucket_cnt + NBUCKET;         // NBUCKET+1
  int* bucket_cursor = bucket_base + NBUCKET + 1;  // NBUCKET
  float* pool = (float*)(bucket_cursor + NBUCKET); // 512*64
  int* cnt = (int*)(pool + NUM_GRAPHS * HID);      // 512
  unsigned* pair_buf = (unsigned*)hf;  // alias: pairs dead before aggregate1 writes hf

  hipMemsetAsync(bucket_cnt, 0, NBUCKET * sizeof(int), stream);
  hipMemsetAsync(pool, 0, NUM_GRAPHS * HID * sizeof(float), stream);
  hipMemsetAsync(cnt, 0, NUM_GRAPHS * sizeof(int), stream);

  // CSR build
  bucket_hist_kernel<<<512, 256, 0, stream>>>(dst, bucket_cnt);
  bucket_scan_kernel<<<1, 64, 0, stream>>>(bucket_cnt, bucket_base, bucket_cursor,
                                           row_ptr);
  pair_scatter_kernel<<<512, 256, 0, stream>>>(src, dst, bucket_cursor, pair_buf);
  bucket_fill_kernel<<<NBUCKET, 256, 0, stream>>>(pair_buf, bucket_base, csr_src,
                                                  row_ptr, dinv);

  const int ggrid = (N_NODES + 63) / 64;
  const int agrid = (N_NODES + 3) / 4;

  // layer 1
  gemm_kernel<IN_DIM><<<ggrid, 256, 0, stream>>>(x, W1, dinv, hp, N_NODES);
  aggregate_kernel<<<agrid, 256, 0, stream>>>(hp, row_ptr, csr_src, dinv, b1, hf, 1);
  // layer 2
  gemm_kernel<HID><<<ggrid, 256, 0, stream>>>(hf, W2, dinv, hp, N_NODES);
  aggregate_kernel<<<agrid, 256, 0, stream>>>(hp, row_ptr, csr_src, dinv, b2, hf, 1);
  // layer 3
  gemm_kernel<HID><<<ggrid, 256, 0, stream>>>(hf, W3, dinv, hp, N_NODES);
  aggregate_pool_kernel<<<agrid, 256, 0, stream>>>(hp, row_ptr, csr_src, dinv, b3,
                                                   batch, pool, cnt);

  // fc
  fc_kernel<<<NUM_GRAPHS, 64, 0, stream>>>(pool, cnt, Wfc, bfc, out);
}

// Round 5
// 499.090 us; speedup vs baseline: 1.2772x; 1.2772x over previous
//
#include <hip/hip_runtime.h>
#include <hip/hip_fp16.h>

#define N_NODES 100000
#define N_EDGES 3200000
#define IN_DIM 128
#define HID 64
#define NUM_GRAPHS 512
#define NUM_CLASSES 10

#define BSHIFT 7
#define BUCKET_W 128
#define NBUCKET ((N_NODES + BUCKET_W - 1) / BUCKET_W)  // 782
#define SRC_BITS 17
#define SRC_MASK ((1 << SRC_BITS) - 1)

// ---------------- CSR build (bucketed, no per-edge global atomics) ----------

__global__ __launch_bounds__(256) void bucket_hist_kernel(const int* __restrict__ dst,
                                                          int* __restrict__ bucket_cnt) {
  __shared__ int h[NBUCKET];
  for (int i = threadIdx.x; i < NBUCKET; i += 256) h[i] = 0;
  __syncthreads();
  int chunk = (N_EDGES + gridDim.x - 1) / gridDim.x;
  int e0 = blockIdx.x * chunk, e1 = min(e0 + chunk, N_EDGES);
  for (int e = e0 + threadIdx.x; e < e1; e += 256)
    atomicAdd(&h[dst[e] >> BSHIFT], 1);
  __syncthreads();
  for (int i = threadIdx.x; i < NBUCKET; i += 256)
    if (h[i]) atomicAdd(&bucket_cnt[i], h[i]);
}

__global__ __launch_bounds__(64) void bucket_scan_kernel(const int* __restrict__ bucket_cnt,
                                                         int* __restrict__ bucket_base,
                                                         int* __restrict__ bucket_cursor,
                                                         int* __restrict__ row_ptr) {
  int lane = threadIdx.x;
  int carry = 0;
  for (int base = 0; base < NBUCKET; base += 64) {
    int i = base + lane;
    int v = (i < NBUCKET) ? bucket_cnt[i] : 0;
    int x = v;
#pragma unroll
    for (int off = 1; off < 64; off <<= 1) {
      int t = __shfl_up(x, off);
      if (lane >= off) x += t;
    }
    if (i < NBUCKET) {
      int ex = carry + x - v;
      bucket_base[i] = ex;
      bucket_cursor[i] = ex;
    }
    carry += __shfl(x, 63);
  }
  if (lane == 0) {
    bucket_base[NBUCKET] = carry;
    row_ptr[N_NODES] = carry;  // == N_EDGES
  }
}

// pair = (dst&127)<<17 | src   (src < 2^17)
__global__ __launch_bounds__(256) void pair_scatter_kernel(const int* __restrict__ src,
                                                           const int* __restrict__ dst,
                                                           int* __restrict__ bucket_cursor,
                                                           unsigned* __restrict__ pair_buf) {
  __shared__ int h[NBUCKET];
  for (int i = threadIdx.x; i < NBUCKET; i += 256) h[i] = 0;
  __syncthreads();
  int chunk = (N_EDGES + gridDim.x - 1) / gridDim.x;
  int e0 = blockIdx.x * chunk, e1 = min(e0 + chunk, N_EDGES);
  for (int e = e0 + threadIdx.x; e < e1; e += 256)
    atomicAdd(&h[dst[e] >> BSHIFT], 1);
  __syncthreads();
  for (int i = threadIdx.x; i < NBUCKET; i += 256) {
    int c = h[i];
    if (c) h[i] = atomicAdd(&bucket_cursor[i], c);
  }
  __syncthreads();
  for (int e = e0 + threadIdx.x; e < e1; e += 256) {
    int d = dst[e];
    int pos = atomicAdd(&h[d >> BSHIFT], 1);  // LDS atomic
    pair_buf[pos] = ((unsigned)(d & (BUCKET_W - 1)) << SRC_BITS) | (unsigned)src[e];
  }
}

__global__ __launch_bounds__(256) void bucket_fill_kernel(const unsigned* __restrict__ pair_buf,
                                                          const int* __restrict__ bucket_base,
                                                          int* __restrict__ csr_src,
                                                          int* __restrict__ row_ptr,
                                                          float* __restrict__ dinv) {
  int b = blockIdx.x;
  int n0 = b << BSHIFT;
  int n1 = min(n0 + BUCKET_W, N_NODES);
  int nn = n1 - n0;
  int eb0 = bucket_base[b], eb1 = bucket_base[b + 1];
  __shared__ int hist[BUCKET_W];
  __shared__ int wtot[2];
  int tid = threadIdx.x;
  if (tid < BUCKET_W) hist[tid] = 0;
  __syncthreads();
  for (int e = eb0 + tid; e < eb1; e += 256)
    atomicAdd(&hist[pair_buf[e] >> SRC_BITS], 1);
  __syncthreads();
  int v = 0, x = 0;
  if (tid < BUCKET_W) {
    v = hist[tid];
    x = v;
#pragma unroll
    for (int off = 1; off < 64; off <<= 1) {
      int t = __shfl_up(x, off);
      if ((tid & 63) >= off) x += t;
    }
    if ((tid & 63) == 63) wtot[tid >> 6] = x;
  }
  __syncthreads();
  if (tid < BUCKET_W) {
    int incl = x + ((tid >= 64) ? wtot[0] : 0);
    int base = eb0 + incl - v;  // exclusive
    if (tid < nn) {
      row_ptr[n0 + tid] = base;
      dinv[n0 + tid] = rsqrtf((float)(v + 1));
    }
    hist[tid] = base;  // becomes the cursor
  }
  __syncthreads();
  for (int e = eb0 + tid; e < eb1; e += 256) {
    unsigned p = pair_buf[e];
    int pos = atomicAdd(&hist[p >> SRC_BITS], 1);  // LDS atomic
    csr_src[pos] = (int)(p & SRC_MASK);
  }
}

// ---------------- GEMM: hp[n][64] = fp16( (A[n][K] @ W[K][64]) * dinv[n] ) --
template <int K>
__global__ __launch_bounds__(256) void gemm_kernel(const float* __restrict__ A,
                                                   const float* __restrict__ W,
                                                   const float* __restrict__ dinv,
                                                   __half* __restrict__ hp, int n) {
  __shared__ float As[64][68];
  __shared__ float Ws[64][64];
  int tid = threadIdx.x;
  int row0 = blockIdx.x * 64;
  int tx = tid & 15, ty = tid >> 4;
  float acc[4][4] = {};
  for (int k0 = 0; k0 < K; k0 += 64) {
    for (int idx = tid * 4; idx < 64 * 64; idx += 1024) {
      int r = idx >> 6, c = idx & 63;
      float4 v = make_float4(0.f, 0.f, 0.f, 0.f);
      if (row0 + r < n)
        v = *(const float4*)&A[(size_t)(row0 + r) * K + k0 + c];
      *(float4*)&As[r][c] = v;
    }
    for (int idx = tid * 4; idx < 64 * 64; idx += 1024) {
      int r = idx >> 6, c = idx & 63;
      *(float4*)&Ws[r][c] = *(const float4*)&W[(size_t)(k0 + r) * 64 + c];
    }
    __syncthreads();
#pragma unroll
    for (int k = 0; k < 64; k += 4) {
      float av[4][4], wv[4][4];
#pragma unroll
      for (int i = 0; i < 4; ++i)
        *(float4*)&av[i][0] = *(float4*)&As[ty * 4 + i][k];
#pragma unroll
      for (int kk = 0; kk < 4; ++kk)
        *(float4*)&wv[kk][0] = *(float4*)&Ws[k + kk][tx * 4];
#pragma unroll
      for (int kk = 0; kk < 4; ++kk)
#pragma unroll
        for (int i = 0; i < 4; ++i)
#pragma unroll
          for (int j = 0; j < 4; ++j)
            acc[i][j] += av[i][kk] * wv[kk][j];
    }
    __syncthreads();
  }
#pragma unroll
  for (int i = 0; i < 4; ++i) {
    int row = row0 + ty * 4 + i;
    if (row < n) {
      float di = dinv[row];
      union {
        uint2 u;
        __half2 h[2];
      } pk;
      pk.h[0] = __floats2half2_rn(acc[i][0] * di, acc[i][1] * di);
      pk.h[1] = __floats2half2_rn(acc[i][2] * di, acc[i][3] * di);
      *(uint2*)&hp[(size_t)row * 64 + tx * 4] = pk.u;
    }
  }
}

// ---------------- Aggregate (half2 gather, 2 edges per instruction) ---------
// hp pre-scaled by dinv. Lanes 0-31 do even edges, 32-63 odd edges; each lane
// covers dims {2l, 2l+1} via half2. Cross-parity combine with shfl_xor(32).
__global__ __launch_bounds__(256) void aggregate_kernel(
    const __half* __restrict__ hp, const int* __restrict__ row_ptr,
    const int* __restrict__ csr_src, const float* __restrict__ dinv,
    const float* __restrict__ bias, float* __restrict__ out, int relu) {
  int node = blockIdx.x * 4 + (threadIdx.x >> 6);
  if (node >= N_NODES) return;
  int lane = threadIdx.x & 63;
  int p = lane >> 5;   // edge parity handled by this half-wave
  int l = lane & 31;   // dim-pair index
  const __half2* hp2 = (const __half2*)hp;
  int beg = row_ptr[node], end = row_ptr[node + 1];
  float2 acc = make_float2(0.f, 0.f), acc2 = make_float2(0.f, 0.f);
  if (p == 0) {  // self loop
    float2 s = __half22float2(hp2[(unsigned)(node * 32 + l)]);
    acc.x = s.x;
    acc.y = s.y;
  }
  int e = beg;
  for (; e + 16 <= end; e += 16) {
    int s0 = csr_src[e + 0 + p];
    int s1 = csr_src[e + 2 + p];
    int s2 = csr_src[e + 4 + p];
    int s3 = csr_src[e + 6 + p];
    int s4 = csr_src[e + 8 + p];
    int s5 = csr_src[e + 10 + p];
    int s6 = csr_src[e + 12 + p];
    int s7 = csr_src[e + 14 + p];
    float2 v0 = __half22float2(hp2[(unsigned)(s0 * 32 + l)]);
    float2 v1 = __half22float2(hp2[(unsigned)(s1 * 32 + l)]);
    float2 v2 = __half22float2(hp2[(unsigned)(s2 * 32 + l)]);
    float2 v3 = __half22float2(hp2[(unsigned)(s3 * 32 + l)]);
    float2 v4 = __half22float2(hp2[(unsigned)(s4 * 32 + l)]);
    float2 v5 = __half22float2(hp2[(unsigned)(s5 * 32 + l)]);
    float2 v6 = __half22float2(hp2[(unsigned)(s6 * 32 + l)]);
    float2 v7 = __half22float2(hp2[(unsigned)(s7 * 32 + l)]);
    acc.x += v0.x + v1.x + v2.x + v3.x;
    acc.y += v0.y + v1.y + v2.y + v3.y;
    acc2.x += v4.x + v5.x + v6.x + v7.x;
    acc2.y += v4.y + v5.y + v6.y + v7.y;
  }
  for (; e + 2 <= end; e += 2) {
    int s = csr_src[e + p];
    float2 v = __half22float2(hp2[(unsigned)(s * 32 + l)]);
    acc.x += v.x;
    acc.y += v.y;
  }
  if (e < end && p == 0) {  // odd leftover edge
    int s = csr_src[e];
    float2 v = __half22float2(hp2[(unsigned)(s * 32 + l)]);
    acc.x += v.x;
    acc.y += v.y;
  }
  acc.x += acc2.x;
  acc.y += acc2.y;
  // combine parities: lane l gets lane l^32's partial
  acc.x += __shfl_xor(acc.x, 32);
  acc.y += __shfl_xor(acc.y, 32);
  if (p == 0) {
    float di = dinv[node];
    float2 b = *(const float2*)&bias[2 * l];
    float2 r;
    r.x = acc.x * di + b.x;
    r.y = acc.y * di + b.y;
    if (relu) {
      r.x = fmaxf(r.x, 0.0f);
      r.y = fmaxf(r.y, 0.0f);
    }
    *(float2*)&out[(unsigned)(node * HID + 2 * l)] = r;
  }
}

// ---------------- Global mean pool (batch sorted) ---------------------------
__global__ __launch_bounds__(256) void pool_kernel(const float* __restrict__ h,
                                                   const int* __restrict__ batch,
                                                   float* __restrict__ pool,
                                                   int* __restrict__ cnt) {
  int waves = gridDim.x * (blockDim.x >> 6);
  int wave = blockIdx.x * (blockDim.x >> 6) + (threadIdx.x >> 6);
  int lane = threadIdx.x & 63;
  int chunk = (N_NODES + waves - 1) / waves;
  int n0 = wave * chunk;
  int n1 = min(n0 + chunk, N_NODES);
  if (n0 >= n1) return;
  int cur = batch[n0];
  float acc = 0.f;
  int c = 0;
  for (int nn = n0; nn < n1; ++nn) {
    int g = batch[nn];
    if (g != cur) {
      atomicAdd(&pool[(size_t)cur * HID + lane], acc);
      if (lane == 0) atomicAdd(&cnt[cur], c);
      acc = 0.f;
      c = 0;
      cur = g;
    }
    acc += h[(size_t)nn * HID + lane];
    ++c;
  }
  atomicAdd(&pool[(size_t)cur * HID + lane], acc);
  if (lane == 0) atomicAdd(&cnt[cur], c);
}

// ---------------- FC ---------------------------------------------------------
__global__ __launch_bounds__(64) void fc_kernel(const float* __restrict__ pool,
                                                const int* __restrict__ cnt,
                                                const float* __restrict__ Wfc,
                                                const float* __restrict__ bfc,
                                                float* __restrict__ out) {
  int g = blockIdx.x;
  int t = threadIdx.x;
  __shared__ float row[64];
  float inv = 1.0f / fmaxf((float)cnt[g], 1.0f);
  row[t] = pool[(size_t)g * HID + t] * inv;
  __syncthreads();
  if (t < NUM_CLASSES) {
    float acc = bfc[t];
#pragma unroll
    for (int k = 0; k < HID; ++k) acc += row[k] * Wfc[k * NUM_CLASSES + t];
    out[(size_t)g * NUM_CLASSES + t] = acc;
  }
}

// ---------------- launch -----------------------------------------------------
extern "C" void kernel_launch(void* const* d_in, const int* in_sizes, int n_in,
                              void* d_out, int out_size, void* d_ws, size_t ws_size,
                              hipStream_t stream) {
  const float* x = (const float*)d_in[0];
  const int* edge_index = (const int*)d_in[1];
  const int* batch = (const int*)d_in[2];
  const float* W1 = (const float*)d_in[3];
  const float* b1 = (const float*)d_in[4];
  const float* W2 = (const float*)d_in[5];
  const float* b2 = (const float*)d_in[6];
  const float* W3 = (const float*)d_in[7];
  const float* b3 = (const float*)d_in[8];
  const float* Wfc = (const float*)d_in[9];
  const float* bfc = (const float*)d_in[10];
  float* out = (float*)d_out;

  const int* src = edge_index;
  const int* dst = edge_index + N_EDGES;

  // workspace layout
  char* w = (char*)d_ws;
  float* hf = (float*)w;                           // N*64 fp32 (aggregate out / GEMM A)
  __half* hp = (__half*)(hf + (size_t)N_NODES * HID);  // N*64 fp16 (gather buf)
  float* dinv = (float*)(hp + (size_t)N_NODES * HID);  // N floats
  int* row_ptr = (int*)(dinv + N_NODES);           // N+1
  int* csr_src = row_ptr + (N_NODES + 1);          // E
  int* bucket_cnt = csr_src + N_EDGES;             // NBUCKET
  int* bucket_base = bucket_cnt + NBUCKET;         // NBUCKET+1
  int* bucket_cursor = bucket_base + NBUCKET + 1;  // NBUCKET
  float* pool = (float*)(bucket_cursor + NBUCKET); // 512*64
  int* cnt = (int*)(pool + NUM_GRAPHS * HID);      // 512
  unsigned* pair_buf = (unsigned*)hf;  // alias: pairs dead before aggregate1 writes hf

  hipMemsetAsync(bucket_cnt, 0, NBUCKET * sizeof(int), stream);
  hipMemsetAsync(pool, 0, NUM_GRAPHS * HID * sizeof(float), stream);
  hipMemsetAsync(cnt, 0, NUM_GRAPHS * sizeof(int), stream);

  // CSR build
  bucket_hist_kernel<<<512, 256, 0, stream>>>(dst, bucket_cnt);
  bucket_scan_kernel<<<1, 64, 0, stream>>>(bucket_cnt, bucket_base, bucket_cursor,
                                           row_ptr);
  pair_scatter_kernel<<<512, 256, 0, stream>>>(src, dst, bucket_cursor, pair_buf);
  bucket_fill_kernel<<<NBUCKET, 256, 0, stream>>>(pair_buf, bucket_base, csr_src,
                                                  row_ptr, dinv);

  const int ggrid = (N_NODES + 63) / 64;
  const int agrid = (N_NODES + 3) / 4;

  // layer 1
  gemm_kernel<IN_DIM><<<ggrid, 256, 0, stream>>>(x, W1, dinv, hp, N_NODES);
  aggregate_kernel<<<agrid, 256, 0, stream>>>(hp, row_ptr, csr_src, dinv, b1, hf, 1);
  // layer 2
  gemm_kernel<HID><<<ggrid, 256, 0, stream>>>(hf, W2, dinv, hp, N_NODES);
  aggregate_kernel<<<agrid, 256, 0, stream>>>(hp, row_ptr, csr_src, dinv, b2, hf, 1);
  // layer 3
  gemm_kernel<HID><<<ggrid, 256, 0, stream>>>(hf, W3, dinv, hp, N_NODES);
  aggregate_kernel<<<agrid, 256, 0, stream>>>(hp, row_ptr, csr_src, dinv, b3, hf, 0);

  // pool + fc
  pool_kernel<<<512, 256, 0, stream>>>(hf, batch, pool, cnt);
  fc_kernel<<<NUM_GRAPHS, 64, 0, stream>>>(pool, cnt, Wfc, bfc, out);
}

// Round 6
// 430.587 us; speedup vs baseline: 1.4804x; 1.1591x over previous
//
#include <hip/hip_runtime.h>
#include <hip/hip_fp16.h>

#define N_NODES 100000
#define N_EDGES 3200000
#define IN_DIM 128
#define HID 64
#define NUM_GRAPHS 512
#define NUM_CLASSES 10

#define BSHIFT 9
#define BUCKET_W 512
#define NBUCKET ((N_NODES + BUCKET_W - 1) / BUCKET_W)  // 196
#define SRC_BITS 17
#define SRC_MASK ((1 << SRC_BITS) - 1)

// ---------------- CSR build (bucketed, no per-edge global atomics) ----------

// 256 blocks, int4 edge reads, LDS hist of 196 bins, aggregated global merge.
__global__ __launch_bounds__(256) void bucket_hist_kernel(const int* __restrict__ dst,
                                                          int* __restrict__ bucket_cnt) {
  __shared__ int h[NBUCKET];
  for (int i = threadIdx.x; i < NBUCKET; i += 256) h[i] = 0;
  __syncthreads();
  const int4* d4 = (const int4*)dst;
  const int nv = N_EDGES / 4 / 256;  // 3125 vectors per block
  int v0 = blockIdx.x * nv, v1 = v0 + nv;
  for (int v = v0 + threadIdx.x; v < v1; v += 256) {
    int4 d = d4[v];
    atomicAdd(&h[d.x >> BSHIFT], 1);
    atomicAdd(&h[d.y >> BSHIFT], 1);
    atomicAdd(&h[d.z >> BSHIFT], 1);
    atomicAdd(&h[d.w >> BSHIFT], 1);
  }
  __syncthreads();
  for (int i = threadIdx.x; i < NBUCKET; i += 256)
    if (h[i]) atomicAdd(&bucket_cnt[i], h[i]);
}

__global__ __launch_bounds__(64) void bucket_scan_kernel(const int* __restrict__ bucket_cnt,
                                                         int* __restrict__ bucket_base,
                                                         int* __restrict__ bucket_cursor,
                                                         int* __restrict__ row_ptr) {
  int lane = threadIdx.x;
  int carry = 0;
  for (int base = 0; base < NBUCKET; base += 64) {
    int i = base + lane;
    int v = (i < NBUCKET) ? bucket_cnt[i] : 0;
    int x = v;
#pragma unroll
    for (int off = 1; off < 64; off <<= 1) {
      int t = __shfl_up(x, off);
      if (lane >= off) x += t;
    }
    if (i < NBUCKET) {
      int ex = carry + x - v;
      bucket_base[i] = ex;
      bucket_cursor[i] = ex;
    }
    carry += __shfl(x, 63);
  }
  if (lane == 0) {
    bucket_base[NBUCKET] = carry;
    row_ptr[N_NODES] = carry;  // == N_EDGES
  }
}

// pair = (dst&511)<<17 | src   (src < 2^17, 26 bits total)
__global__ __launch_bounds__(256) void pair_scatter_kernel(const int* __restrict__ src,
                                                           const int* __restrict__ dst,
                                                           int* __restrict__ bucket_cursor,
                                                           unsigned* __restrict__ pair_buf) {
  __shared__ int h[NBUCKET];
  for (int i = threadIdx.x; i < NBUCKET; i += 256) h[i] = 0;
  __syncthreads();
  const int4* d4 = (const int4*)dst;
  const int4* s4 = (const int4*)src;
  const int nv = N_EDGES / 4 / 256;  // 3125
  int v0 = blockIdx.x * nv, v1 = v0 + nv;
  for (int v = v0 + threadIdx.x; v < v1; v += 256) {
    int4 d = d4[v];
    atomicAdd(&h[d.x >> BSHIFT], 1);
    atomicAdd(&h[d.y >> BSHIFT], 1);
    atomicAdd(&h[d.z >> BSHIFT], 1);
    atomicAdd(&h[d.w >> BSHIFT], 1);
  }
  __syncthreads();
  for (int i = threadIdx.x; i < NBUCKET; i += 256) {
    int c = h[i];
    if (c) h[i] = atomicAdd(&bucket_cursor[i], c);
  }
  __syncthreads();
  for (int v = v0 + threadIdx.x; v < v1; v += 256) {
    int4 d = d4[v];
    int4 s = s4[v];
    int p0 = atomicAdd(&h[d.x >> BSHIFT], 1);
    pair_buf[p0] = ((unsigned)(d.x & (BUCKET_W - 1)) << SRC_BITS) | (unsigned)s.x;
    int p1 = atomicAdd(&h[d.y >> BSHIFT], 1);
    pair_buf[p1] = ((unsigned)(d.y & (BUCKET_W - 1)) << SRC_BITS) | (unsigned)s.y;
    int p2 = atomicAdd(&h[d.z >> BSHIFT], 1);
    pair_buf[p2] = ((unsigned)(d.z & (BUCKET_W - 1)) << SRC_BITS) | (unsigned)s.z;
    int p3 = atomicAdd(&h[d.w >> BSHIFT], 1);
    pair_buf[p3] = ((unsigned)(d.w & (BUCKET_W - 1)) << SRC_BITS) | (unsigned)s.w;
  }
}

// one block per 512-node bucket: LDS hist(512) -> scan -> row_ptr/dinv -> fill
__global__ __launch_bounds__(256) void bucket_fill_kernel(const unsigned* __restrict__ pair_buf,
                                                          const int* __restrict__ bucket_base,
                                                          int* __restrict__ csr_src,
                                                          int* __restrict__ row_ptr,
                                                          float* __restrict__ dinv) {
  int b = blockIdx.x;
  int n0 = b << BSHIFT;
  int nn = min(BUCKET_W, N_NODES - n0);
  int eb0 = bucket_base[b], eb1 = bucket_base[b + 1];
  __shared__ int hist[BUCKET_W];
  __shared__ int wsum[4];
  int tid = threadIdx.x;
  hist[tid] = 0;
  hist[tid + 256] = 0;
  __syncthreads();
  for (int e = eb0 + tid; e < eb1; e += 256)
    atomicAdd(&hist[pair_buf[e] >> SRC_BITS], 1);
  __syncthreads();
  // scan 512 bins, thread t owns bins 2t, 2t+1
  int h0 = hist[2 * tid], h1 = hist[2 * tid + 1];
  int v = h0 + h1;
  int lane = tid & 63, wid = tid >> 6;
  int x = v;
#pragma unroll
  for (int off = 1; off < 64; off <<= 1) {
    int t = __shfl_up(x, off);
    if (lane >= off) x += t;
  }
  if (lane == 63) wsum[wid] = x;
  __syncthreads();
  if (tid == 0) {
    int c = 0;
#pragma unroll
    for (int i = 0; i < 4; ++i) {
      int t = wsum[i];
      wsum[i] = c;
      c += t;
    }
  }
  __syncthreads();
  int base0 = eb0 + x - v + wsum[wid];  // exclusive
  int base1 = base0 + h0;
  if (2 * tid < nn) {
    row_ptr[n0 + 2 * tid] = base0;
    dinv[n0 + 2 * tid] = rsqrtf((float)(h0 + 1));
  }
  if (2 * tid + 1 < nn) {
    row_ptr[n0 + 2 * tid + 1] = base1;
    dinv[n0 + 2 * tid + 1] = rsqrtf((float)(h1 + 1));
  }
  __syncthreads();
  hist[2 * tid] = base0;
  hist[2 * tid + 1] = base1;
  __syncthreads();
  for (int e = eb0 + tid; e < eb1; e += 256) {
    unsigned p = pair_buf[e];
    int pos = atomicAdd(&hist[p >> SRC_BITS], 1);  // LDS atomic
    csr_src[pos] = (int)(p & SRC_MASK);
  }
}

// ---------------- GEMM: hp[n][64] = fp16( (A[n][K] @ W[K][64]) * dinv[n] ) --
template <int K>
__global__ __launch_bounds__(256) void gemm_kernel(const float* __restrict__ A,
                                                   const float* __restrict__ W,
                                                   const float* __restrict__ dinv,
                                                   __half* __restrict__ hp, int n) {
  __shared__ float As[64][68];
  __shared__ float Ws[64][64];
  int tid = threadIdx.x;
  int row0 = blockIdx.x * 64;
  int tx = tid & 15, ty = tid >> 4;
  float acc[4][4] = {};
  for (int k0 = 0; k0 < K; k0 += 64) {
    for (int idx = tid * 4; idx < 64 * 64; idx += 1024) {
      int r = idx >> 6, c = idx & 63;
      float4 v = make_float4(0.f, 0.f, 0.f, 0.f);
      if (row0 + r < n)
        v = *(const float4*)&A[(size_t)(row0 + r) * K + k0 + c];
      *(float4*)&As[r][c] = v;
    }
    for (int idx = tid * 4; idx < 64 * 64; idx += 1024) {
      int r = idx >> 6, c = idx & 63;
      *(float4*)&Ws[r][c] = *(const float4*)&W[(size_t)(k0 + r) * 64 + c];
    }
    __syncthreads();
#pragma unroll
    for (int k = 0; k < 64; k += 4) {
      float av[4][4], wv[4][4];
#pragma unroll
      for (int i = 0; i < 4; ++i)
        *(float4*)&av[i][0] = *(float4*)&As[ty * 4 + i][k];
#pragma unroll
      for (int kk = 0; kk < 4; ++kk)
        *(float4*)&wv[kk][0] = *(float4*)&Ws[k + kk][tx * 4];
#pragma unroll
      for (int kk = 0; kk < 4; ++kk)
#pragma unroll
        for (int i = 0; i < 4; ++i)
#pragma unroll
          for (int j = 0; j < 4; ++j)
            acc[i][j] += av[i][kk] * wv[kk][j];
    }
    __syncthreads();
  }
#pragma unroll
  for (int i = 0; i < 4; ++i) {
    int row = row0 + ty * 4 + i;
    if (row < n) {
      float di = dinv[row];
      union {
        uint2 u;
        __half2 h[2];
      } pk;
      pk.h[0] = __floats2half2_rn(acc[i][0] * di, acc[i][1] * di);
      pk.h[1] = __floats2half2_rn(acc[i][2] * di, acc[i][3] * di);
      *(uint2*)&hp[(size_t)row * 64 + tx * 4] = pk.u;
    }
  }
}

// ---------------- Aggregate (half2 gather, tiered unroll for ILP) -----------
// hp pre-scaled by dinv. Lanes 0-31 even edges, 32-63 odd; lane covers dims
// {2l,2l+1}. Tiers of 32/16/8/4/2 edges keep up to 16 gathers in flight.
#define GATH(H)                                                      \
  {                                                                  \
    int s_[H];                                                       \
    _Pragma("unroll") for (int i_ = 0; i_ < H; ++i_)                 \
        s_[i_] = csr_src[e + 2 * i_ + p];                            \
    float2 v_[H];                                                    \
    _Pragma("unroll") for (int i_ = 0; i_ < H; ++i_)                 \
        v_[i_] = __half22float2(hp2[(unsigned)(s_[i_] * 32 + l)]);   \
    _Pragma("unroll") for (int i_ = 0; i_ < H; ++i_) {               \
      acc.x += v_[i_].x;                                             \
      acc.y += v_[i_].y;                                             \
    }                                                                \
  }

__global__ __launch_bounds__(256) void aggregate_kernel(
    const __half* __restrict__ hp, const int* __restrict__ row_ptr,
    const int* __restrict__ csr_src, const float* __restrict__ dinv,
    const float* __restrict__ bias, float* __restrict__ out, int relu) {
  int node = blockIdx.x * 4 + (threadIdx.x >> 6);
  if (node >= N_NODES) return;
  int lane = threadIdx.x & 63;
  int p = lane >> 5;  // edge parity for this half-wave
  int l = lane & 31;  // dim-pair index
  const __half2* hp2 = (const __half2*)hp;
  int beg = row_ptr[node], end = row_ptr[node + 1];
  float2 acc = make_float2(0.f, 0.f);
  if (p == 0) {  // self loop
    float2 s = __half22float2(hp2[(unsigned)(node * 32 + l)]);
    acc.x = s.x;
    acc.y = s.y;
  }
  int e = beg;
  int rem = end - beg;
  while (rem >= 32) {
    GATH(16);
    e += 32;
    rem -= 32;
  }
  if (rem >= 16) {
    GATH(8);
    e += 16;
    rem -= 16;
  }
  if (rem >= 8) {
    GATH(4);
    e += 8;
    rem -= 8;
  }
  if (rem >= 4) {
    GATH(2);
    e += 4;
    rem -= 4;
  }
  if (rem >= 2) {
    GATH(1);
    e += 2;
    rem -= 2;
  }
  if (rem && p == 0) {
    float2 v = __half22float2(hp2[(unsigned)(csr_src[e] * 32 + l)]);
    acc.x += v.x;
    acc.y += v.y;
  }
  // combine parities
  acc.x += __shfl_xor(acc.x, 32);
  acc.y += __shfl_xor(acc.y, 32);
  if (p == 0) {
    float di = dinv[node];
    float2 b = *(const float2*)&bias[2 * l];
    float2 r;
    r.x = acc.x * di + b.x;
    r.y = acc.y * di + b.y;
    if (relu) {
      r.x = fmaxf(r.x, 0.0f);
      r.y = fmaxf(r.y, 0.0f);
    }
    *(float2*)&out[(unsigned)(node * HID + 2 * l)] = r;
  }
}

// ---------------- Global mean pool (batch sorted) ---------------------------
__global__ __launch_bounds__(256) void pool_kernel(const float* __restrict__ h,
                                                   const int* __restrict__ batch,
                                                   float* __restrict__ pool,
                                                   int* __restrict__ cnt) {
  int waves = gridDim.x * (blockDim.x >> 6);
  int wave = blockIdx.x * (blockDim.x >> 6) + (threadIdx.x >> 6);
  int lane = threadIdx.x & 63;
  int chunk = (N_NODES + waves - 1) / waves;
  int n0 = wave * chunk;
  int n1 = min(n0 + chunk, N_NODES);
  if (n0 >= n1) return;
  int cur = batch[n0];
  float acc = 0.f;
  int c = 0;
  for (int nn = n0; nn < n1; ++nn) {
    int g = batch[nn];
    if (g != cur) {
      atomicAdd(&pool[(size_t)cur * HID + lane], acc);
      if (lane == 0) atomicAdd(&cnt[cur], c);
      acc = 0.f;
      c = 0;
      cur = g;
    }
    acc += h[(size_t)nn * HID + lane];
    ++c;
  }
  atomicAdd(&pool[(size_t)cur * HID + lane], acc);
  if (lane == 0) atomicAdd(&cnt[cur], c);
}

// ---------------- FC ---------------------------------------------------------
__global__ __launch_bounds__(64) void fc_kernel(const float* __restrict__ pool,
                                                const int* __restrict__ cnt,
                                                const float* __restrict__ Wfc,
                                                const float* __restrict__ bfc,
                                                float* __restrict__ out) {
  int g = blockIdx.x;
  int t = threadIdx.x;
  __shared__ float row[64];
  float inv = 1.0f / fmaxf((float)cnt[g], 1.0f);
  row[t] = pool[(size_t)g * HID + t] * inv;
  __syncthreads();
  if (t < NUM_CLASSES) {
    float acc = bfc[t];
#pragma unroll
    for (int k = 0; k < HID; ++k) acc += row[k] * Wfc[k * NUM_CLASSES + t];
    out[(size_t)g * NUM_CLASSES + t] = acc;
  }
}

// ---------------- launch -----------------------------------------------------
extern "C" void kernel_launch(void* const* d_in, const int* in_sizes, int n_in,
                              void* d_out, int out_size, void* d_ws, size_t ws_size,
                              hipStream_t stream) {
  const float* x = (const float*)d_in[0];
  const int* edge_index = (const int*)d_in[1];
  const int* batch = (const int*)d_in[2];
  const float* W1 = (const float*)d_in[3];
  const float* b1 = (const float*)d_in[4];
  const float* W2 = (const float*)d_in[5];
  const float* b2 = (const float*)d_in[6];
  const float* W3 = (const float*)d_in[7];
  const float* b3 = (const float*)d_in[8];
  const float* Wfc = (const float*)d_in[9];
  const float* bfc = (const float*)d_in[10];
  float* out = (float*)d_out;

  const int* src = edge_index;
  const int* dst = edge_index + N_EDGES;

  // workspace layout
  char* w = (char*)d_ws;
  float* hf = (float*)w;                           // N*64 fp32 (aggregate out / GEMM A)
  __half* hp = (__half*)(hf + (size_t)N_NODES * HID);  // N*64 fp16 (gather buf)
  float* dinv = (float*)(hp + (size_t)N_NODES * HID);  // N floats
  int* row_ptr = (int*)(dinv + N_NODES);           // N+1
  int* csr_src = row_ptr + (N_NODES + 1);          // E
  int* bucket_cnt = csr_src + N_EDGES;             // NBUCKET
  int* bucket_base = bucket_cnt + NBUCKET;         // NBUCKET+1
  int* bucket_cursor = bucket_base + NBUCKET + 1;  // NBUCKET
  float* pool = (float*)(bucket_cursor + NBUCKET); // 512*64
  int* cnt = (int*)(pool + NUM_GRAPHS * HID);      // 512
  unsigned* pair_buf = (unsigned*)hf;  // alias: pairs dead before aggregate1 writes hf

  hipMemsetAsync(bucket_cnt, 0, NBUCKET * sizeof(int), stream);
  hipMemsetAsync(pool, 0, NUM_GRAPHS * HID * sizeof(float), stream);
  hipMemsetAsync(cnt, 0, NUM_GRAPHS * sizeof(int), stream);

  // CSR build
  bucket_hist_kernel<<<256, 256, 0, stream>>>(dst, bucket_cnt);
  bucket_scan_kernel<<<1, 64, 0, stream>>>(bucket_cnt, bucket_base, bucket_cursor,
                                           row_ptr);
  pair_scatter_kernel<<<256, 256, 0, stream>>>(src, dst, bucket_cursor, pair_buf);
  bucket_fill_kernel<<<NBUCKET, 256, 0, stream>>>(pair_buf, bucket_base, csr_src,
                                                  row_ptr, dinv);

  const int ggrid = (N_NODES + 63) / 64;
  const int agrid = (N_NODES + 3) / 4;

  // layer 1
  gemm_kernel<IN_DIM><<<ggrid, 256, 0, stream>>>(x, W1, dinv, hp, N_NODES);
  aggregate_kernel<<<agrid, 256, 0, stream>>>(hp, row_ptr, csr_src, dinv, b1, hf, 1);
  // layer 2
  gemm_kernel<HID><<<ggrid, 256, 0, stream>>>(hf, W2, dinv, hp, N_NODES);
  aggregate_kernel<<<agrid, 256, 0, stream>>>(hp, row_ptr, csr_src, dinv, b2, hf, 1);
  // layer 3
  gemm_kernel<HID><<<ggrid, 256, 0, stream>>>(hf, W3, dinv, hp, N_NODES);
  aggregate_kernel<<<agrid, 256, 0, stream>>>(hp, row_ptr, csr_src, dinv, b3, hf, 0);

  // pool + fc
  pool_kernel<<<512, 256, 0, stream>>>(hf, batch, pool, cnt);
  fc_kernel<<<NUM_GRAPHS, 64, 0, stream>>>(pool, cnt, Wfc, bfc, out);
}

// Round 7
// 343.239 us; speedup vs baseline: 1.8571x; 1.2545x over previous
//
#include <hip/hip_runtime.h>
#include <hip/hip_fp16.h>

#define N_NODES 100000
#define N_EDGES 3200000
#define IN_DIM 128
#define HID 64
#define NUM_GRAPHS 512
#define NUM_CLASSES 10

#define BSHIFT 9
#define BUCKET_W 512
#define NBUCKET ((N_NODES + BUCKET_W - 1) / BUCKET_W)  // 196
#define SRC_BITS 17
#define SRC_MASK ((1 << SRC_BITS) - 1)

typedef _Float16 f16;
typedef f16 f16x8 __attribute__((ext_vector_type(8)));
typedef float f32x4 __attribute__((ext_vector_type(4)));

// ---------------- CSR build (bucketed, no per-edge global atomics) ----------

// 256 blocks, int4 edge reads, LDS hist; persists per-block hist for scatter.
__global__ __launch_bounds__(256) void bucket_hist_kernel(const int* __restrict__ dst,
                                                          int* __restrict__ bucket_cnt,
                                                          int* __restrict__ blk_hist) {
  __shared__ int h[NBUCKET];
  for (int i = threadIdx.x; i < NBUCKET; i += 256) h[i] = 0;
  __syncthreads();
  const int4* d4 = (const int4*)dst;
  const int nv = N_EDGES / 4 / 256;  // 3125 vectors per block
  int v0 = blockIdx.x * nv, v1 = v0 + nv;
  for (int v = v0 + threadIdx.x; v < v1; v += 256) {
    int4 d = d4[v];
    atomicAdd(&h[d.x >> BSHIFT], 1);
    atomicAdd(&h[d.y >> BSHIFT], 1);
    atomicAdd(&h[d.z >> BSHIFT], 1);
    atomicAdd(&h[d.w >> BSHIFT], 1);
  }
  __syncthreads();
  for (int i = threadIdx.x; i < NBUCKET; i += 256) {
    int c = h[i];
    blk_hist[blockIdx.x * NBUCKET + i] = c;
    if (c) atomicAdd(&bucket_cnt[i], c);
  }
}

__global__ __launch_bounds__(64) void bucket_scan_kernel(const int* __restrict__ bucket_cnt,
                                                         int* __restrict__ bucket_base,
                                                         int* __restrict__ bucket_cursor,
                                                         int* __restrict__ row_ptr) {
  int lane = threadIdx.x;
  int carry = 0;
  for (int base = 0; base < NBUCKET; base += 64) {
    int i = base + lane;
    int v = (i < NBUCKET) ? bucket_cnt[i] : 0;
    int x = v;
#pragma unroll
    for (int off = 1; off < 64; off <<= 1) {
      int t = __shfl_up(x, off);
      if (lane >= off) x += t;
    }
    if (i < NBUCKET) {
      int ex = carry + x - v;
      bucket_base[i] = ex;
      bucket_cursor[i] = ex;
    }
    carry += __shfl(x, 63);
  }
  if (lane == 0) {
    bucket_base[NBUCKET] = carry;
    row_ptr[N_NODES] = carry;  // == N_EDGES
  }
}

// pair = (dst&511)<<17 | src. Uses persisted blk_hist (no re-histogram pass).
__global__ __launch_bounds__(256) void pair_scatter_kernel(const int* __restrict__ src,
                                                           const int* __restrict__ dst,
                                                           int* __restrict__ bucket_cursor,
                                                           const int* __restrict__ blk_hist,
                                                           unsigned* __restrict__ pair_buf) {
  __shared__ int h[NBUCKET];
  for (int i = threadIdx.x; i < NBUCKET; i += 256) {
    int c = blk_hist[blockIdx.x * NBUCKET + i];
    h[i] = c ? atomicAdd(&bucket_cursor[i], c) : 0;
  }
  __syncthreads();
  const int4* d4 = (const int4*)dst;
  const int4* s4 = (const int4*)src;
  const int nv = N_EDGES / 4 / 256;  // 3125
  int v0 = blockIdx.x * nv, v1 = v0 + nv;
  for (int v = v0 + threadIdx.x; v < v1; v += 256) {
    int4 d = d4[v];
    int4 s = s4[v];
    int p0 = atomicAdd(&h[d.x >> BSHIFT], 1);
    pair_buf[p0] = ((unsigned)(d.x & (BUCKET_W - 1)) << SRC_BITS) | (unsigned)s.x;
    int p1 = atomicAdd(&h[d.y >> BSHIFT], 1);
    pair_buf[p1] = ((unsigned)(d.y & (BUCKET_W - 1)) << SRC_BITS) | (unsigned)s.y;
    int p2 = atomicAdd(&h[d.z >> BSHIFT], 1);
    pair_buf[p2] = ((unsigned)(d.z & (BUCKET_W - 1)) << SRC_BITS) | (unsigned)s.z;
    int p3 = atomicAdd(&h[d.w >> BSHIFT], 1);
    pair_buf[p3] = ((unsigned)(d.w & (BUCKET_W - 1)) << SRC_BITS) | (unsigned)s.w;
  }
}

// one block per 512-node bucket: LDS hist(512) -> scan -> row_ptr/dinv -> fill
__global__ __launch_bounds__(256) void bucket_fill_kernel(const unsigned* __restrict__ pair_buf,
                                                          const int* __restrict__ bucket_base,
                                                          int* __restrict__ csr_src,
                                                          int* __restrict__ row_ptr,
                                                          float* __restrict__ dinv) {
  int b = blockIdx.x;
  int n0 = b << BSHIFT;
  int nn = min(BUCKET_W, N_NODES - n0);
  int eb0 = bucket_base[b], eb1 = bucket_base[b + 1];
  __shared__ int hist[BUCKET_W];
  __shared__ int wsum[4];
  int tid = threadIdx.x;
  hist[tid] = 0;
  hist[tid + 256] = 0;
  __syncthreads();
  for (int e = eb0 + tid; e < eb1; e += 256)
    atomicAdd(&hist[pair_buf[e] >> SRC_BITS], 1);
  __syncthreads();
  int h0 = hist[2 * tid], h1 = hist[2 * tid + 1];
  int v = h0 + h1;
  int lane = tid & 63, wid = tid >> 6;
  int x = v;
#pragma unroll
  for (int off = 1; off < 64; off <<= 1) {
    int t = __shfl_up(x, off);
    if (lane >= off) x += t;
  }
  if (lane == 63) wsum[wid] = x;
  __syncthreads();
  if (tid == 0) {
    int c = 0;
#pragma unroll
    for (int i = 0; i < 4; ++i) {
      int t = wsum[i];
      wsum[i] = c;
      c += t;
    }
  }
  __syncthreads();
  int base0 = eb0 + x - v + wsum[wid];
  int base1 = base0 + h0;
  if (2 * tid < nn) {
    row_ptr[n0 + 2 * tid] = base0;
    dinv[n0 + 2 * tid] = rsqrtf((float)(h0 + 1));
  }
  if (2 * tid + 1 < nn) {
    row_ptr[n0 + 2 * tid + 1] = base1;
    dinv[n0 + 2 * tid + 1] = rsqrtf((float)(h1 + 1));
  }
  __syncthreads();
  hist[2 * tid] = base0;
  hist[2 * tid + 1] = base1;
  __syncthreads();
  for (int e = eb0 + tid; e < eb1; e += 256) {
    unsigned p = pair_buf[e];
    int pos = atomicAdd(&hist[p >> SRC_BITS], 1);
    csr_src[pos] = (int)(p & SRC_MASK);
  }
}

// ---------------- MFMA GEMM: hp[n][64] = f16((A[n][K]@W[K][64])*dinv[n]) ----
// 256 threads = 4 waves; block tile 64 rows; wave w -> rows 16w..16w+16,
// 4 col-tiles of 16. mfma_f32_16x16x32_f16 per (col-tile, K-step).
template <int K, bool SRC_F32>
__global__ __launch_bounds__(256) void mfma_gemm_kernel(const void* __restrict__ Asrc,
                                                        const float* __restrict__ W,
                                                        const float* __restrict__ dinv,
                                                        f16* __restrict__ hp, int n) {
  __shared__ f16 Ah[64][K + 8];
  __shared__ f16 Wt[64][K + 8];  // Wt[c][k] = W[k][c]
  int tid = threadIdx.x;
  int row0 = blockIdx.x * 64;
  // stage W^T (coalesced read, f16 convert)
  for (int idx = tid; idx < K * 64; idx += 256) {
    int k = idx >> 6, c = idx & 63;
    Wt[c][k] = (f16)W[idx];
  }
  // stage A
  if (SRC_F32) {
    const float* A = (const float*)Asrc;
    for (int idx = tid * 4; idx < 64 * K; idx += 1024) {
      int r = idx / K, c = idx % K;
      float4 v = make_float4(0.f, 0.f, 0.f, 0.f);
      if (row0 + r < n) v = *(const float4*)&A[(size_t)(row0 + r) * K + c];
      Ah[r][c] = (f16)v.x;
      Ah[r][c + 1] = (f16)v.y;
      Ah[r][c + 2] = (f16)v.z;
      Ah[r][c + 3] = (f16)v.w;
    }
  } else {
    const f16* A = (const f16*)Asrc;
    for (int idx = tid * 8; idx < 64 * K; idx += 2048) {
      int r = idx / K, c = idx % K;
      uint4 z = make_uint4(0u, 0u, 0u, 0u);
      if (row0 + r < n) z = *(const uint4*)&A[(size_t)(row0 + r) * K + c];
      *(uint4*)&Ah[r][c] = z;
    }
  }
  __syncthreads();
  int w = tid >> 6, lane = tid & 63;
  int m0 = 16 * w;
  int arow = m0 + (lane & 15);
  int kbase = (lane >> 4) * 8;
  f32x4 acc[4] = {};
#pragma unroll
  for (int ks = 0; ks < K / 32; ++ks) {
    f16x8 a = *(const f16x8*)&Ah[arow][32 * ks + kbase];
#pragma unroll
    for (int t = 0; t < 4; ++t) {
      f16x8 b = *(const f16x8*)&Wt[16 * t + (lane & 15)][32 * ks + kbase];
      acc[t] = __builtin_amdgcn_mfma_f32_16x16x32_f16(a, b, acc[t], 0, 0, 0);
    }
  }
  // epilogue: C row = m0 + (lane>>4)*4 + j, col = 16t + (lane&15)
#pragma unroll
  for (int j = 0; j < 4; ++j) {
    int grow = row0 + m0 + (lane >> 4) * 4 + j;
    if (grow < n) {
      float di = dinv[grow];
#pragma unroll
      for (int t = 0; t < 4; ++t)
        hp[(size_t)grow * 64 + 16 * t + (lane & 15)] = (f16)(acc[t][j] * di);
    }
  }
}

// ---------------- Aggregate (half2 gather, tiered unroll, fp16 out) ---------
#define GATH(H)                                                      \
  {                                                                  \
    int s_[H];                                                       \
    _Pragma("unroll") for (int i_ = 0; i_ < H; ++i_)                 \
        s_[i_] = csr_src[e + 2 * i_ + p];                            \
    float2 v_[H];                                                    \
    _Pragma("unroll") for (int i_ = 0; i_ < H; ++i_)                 \
        v_[i_] = __half22float2(hp2[(unsigned)(s_[i_] * 32 + l)]);   \
    _Pragma("unroll") for (int i_ = 0; i_ < H; ++i_) {               \
      acc.x += v_[i_].x;                                             \
      acc.y += v_[i_].y;                                             \
    }                                                                \
  }

__global__ __launch_bounds__(256) void aggregate_kernel(
    const __half* __restrict__ hp, const int* __restrict__ row_ptr,
    const int* __restrict__ csr_src, const float* __restrict__ dinv,
    const float* __restrict__ bias, __half* __restrict__ out, int relu) {
  int node = blockIdx.x * 4 + (threadIdx.x >> 6);
  if (node >= N_NODES) return;
  int lane = threadIdx.x & 63;
  int p = lane >> 5;
  int l = lane & 31;
  const __half2* hp2 = (const __half2*)hp;
  int beg = row_ptr[node], end = row_ptr[node + 1];
  float2 acc = make_float2(0.f, 0.f);
  if (p == 0) {  // self loop
    float2 s = __half22float2(hp2[(unsigned)(node * 32 + l)]);
    acc.x = s.x;
    acc.y = s.y;
  }
  int e = beg;
  int rem = end - beg;
  while (rem >= 32) {
    GATH(16);
    e += 32;
    rem -= 32;
  }
  if (rem >= 16) {
    GATH(8);
    e += 16;
    rem -= 16;
  }
  if (rem >= 8) {
    GATH(4);
    e += 8;
    rem -= 8;
  }
  if (rem >= 4) {
    GATH(2);
    e += 4;
    rem -= 4;
  }
  if (rem >= 2) {
    GATH(1);
    e += 2;
    rem -= 2;
  }
  if (rem && p == 0) {
    float2 v = __half22float2(hp2[(unsigned)(csr_src[e] * 32 + l)]);
    acc.x += v.x;
    acc.y += v.y;
  }
  acc.x += __shfl_xor(acc.x, 32);
  acc.y += __shfl_xor(acc.y, 32);
  if (p == 0) {
    float di = dinv[node];
    float2 b = *(const float2*)&bias[2 * l];
    float rx = acc.x * di + b.x;
    float ry = acc.y * di + b.y;
    if (relu) {
      rx = fmaxf(rx, 0.0f);
      ry = fmaxf(ry, 0.0f);
    }
    ((__half2*)out)[(unsigned)(node * 32 + l)] = __floats2half2_rn(rx, ry);
  }
}

// ---------------- Global mean pool (batch sorted, fp16 in) ------------------
__global__ __launch_bounds__(256) void pool_kernel(const __half* __restrict__ h,
                                                   const int* __restrict__ batch,
                                                   float* __restrict__ pool,
                                                   int* __restrict__ cnt) {
  int waves = gridDim.x * (blockDim.x >> 6);
  int wave = blockIdx.x * (blockDim.x >> 6) + (threadIdx.x >> 6);
  int lane = threadIdx.x & 63;
  int chunk = (N_NODES + waves - 1) / waves;
  int n0 = wave * chunk;
  int n1 = min(n0 + chunk, N_NODES);
  if (n0 >= n1) return;
  int cur = batch[n0];
  float acc = 0.f;
  int c = 0;
  for (int nn = n0; nn < n1; ++nn) {
    int g = batch[nn];
    if (g != cur) {
      atomicAdd(&pool[(size_t)cur * HID + lane], acc);
      if (lane == 0) atomicAdd(&cnt[cur], c);
      acc = 0.f;
      c = 0;
      cur = g;
    }
    acc += __half2float(h[(size_t)nn * HID + lane]);
    ++c;
  }
  atomicAdd(&pool[(size_t)cur * HID + lane], acc);
  if (lane == 0) atomicAdd(&cnt[cur], c);
}

// ---------------- FC ---------------------------------------------------------
__global__ __launch_bounds__(64) void fc_kernel(const float* __restrict__ pool,
                                                const int* __restrict__ cnt,
                                                const float* __restrict__ Wfc,
                                                const float* __restrict__ bfc,
                                                float* __restrict__ out) {
  int g = blockIdx.x;
  int t = threadIdx.x;
  __shared__ float row[64];
  float inv = 1.0f / fmaxf((float)cnt[g], 1.0f);
  row[t] = pool[(size_t)g * HID + t] * inv;
  __syncthreads();
  if (t < NUM_CLASSES) {
    float acc = bfc[t];
#pragma unroll
    for (int k = 0; k < HID; ++k) acc += row[k] * Wfc[k * NUM_CLASSES + t];
    out[(size_t)g * NUM_CLASSES + t] = acc;
  }
}

// ---------------- launch -----------------------------------------------------
extern "C" void kernel_launch(void* const* d_in, const int* in_sizes, int n_in,
                              void* d_out, int out_size, void* d_ws, size_t ws_size,
                              hipStream_t stream) {
  const float* x = (const float*)d_in[0];
  const int* edge_index = (const int*)d_in[1];
  const int* batch = (const int*)d_in[2];
  const float* W1 = (const float*)d_in[3];
  const float* b1 = (const float*)d_in[4];
  const float* W2 = (const float*)d_in[5];
  const float* b2 = (const float*)d_in[6];
  const float* W3 = (const float*)d_in[7];
  const float* b3 = (const float*)d_in[8];
  const float* Wfc = (const float*)d_in[9];
  const float* bfc = (const float*)d_in[10];
  float* out = (float*)d_out;

  const int* src = edge_index;
  const int* dst = edge_index + N_EDGES;

  // workspace layout
  char* w = (char*)d_ws;
  __half* h16 = (__half*)w;                        // N*64 f16 (aggregate out / GEMM A)
  __half* hp = h16 + (size_t)N_NODES * HID;        // N*64 f16 (GEMM out, gather buf)
  float* dinv = (float*)(hp + (size_t)N_NODES * HID);  // N
  int* row_ptr = (int*)(dinv + N_NODES);           // N+1
  int* csr_src = row_ptr + (N_NODES + 1);          // E
  int* bucket_cnt = csr_src + N_EDGES;             // NBUCKET
  int* bucket_base = bucket_cnt + NBUCKET;         // NBUCKET+1
  int* bucket_cursor = bucket_base + NBUCKET + 1;  // NBUCKET
  float* pool = (float*)(bucket_cursor + NBUCKET); // 512*64
  int* cnt = (int*)(pool + NUM_GRAPHS * HID);      // 512
  int* blk_hist = cnt + NUM_GRAPHS;                // 256*NBUCKET
  unsigned* pair_buf = (unsigned*)h16;  // alias: dead before aggregate1 writes h16

  hipMemsetAsync(bucket_cnt, 0, NBUCKET * sizeof(int), stream);
  hipMemsetAsync(pool, 0, NUM_GRAPHS * HID * sizeof(float), stream);
  hipMemsetAsync(cnt, 0, NUM_GRAPHS * sizeof(int), stream);

  // CSR build
  bucket_hist_kernel<<<256, 256, 0, stream>>>(dst, bucket_cnt, blk_hist);
  bucket_scan_kernel<<<1, 64, 0, stream>>>(bucket_cnt, bucket_base, bucket_cursor,
                                           row_ptr);
  pair_scatter_kernel<<<256, 256, 0, stream>>>(src, dst, bucket_cursor, blk_hist,
                                               pair_buf);
  bucket_fill_kernel<<<NBUCKET, 256, 0, stream>>>(pair_buf, bucket_base, csr_src,
                                                  row_ptr, dinv);

  const int ggrid = (N_NODES + 63) / 64;
  const int agrid = (N_NODES + 3) / 4;

  // layer 1
  mfma_gemm_kernel<IN_DIM, true><<<ggrid, 256, 0, stream>>>(x, W1, dinv, (f16*)hp,
                                                            N_NODES);
  aggregate_kernel<<<agrid, 256, 0, stream>>>(hp, row_ptr, csr_src, dinv, b1, h16, 1);
  // layer 2
  mfma_gemm_kernel<HID, false><<<ggrid, 256, 0, stream>>>(h16, W2, dinv, (f16*)hp,
                                                          N_NODES);
  aggregate_kernel<<<agrid, 256, 0, stream>>>(hp, row_ptr, csr_src, dinv, b2, h16, 1);
  // layer 3
  mfma_gemm_kernel<HID, false><<<ggrid, 256, 0, stream>>>(h16, W3, dinv, (f16*)hp,
                                                          N_NODES);
  aggregate_kernel<<<agrid, 256, 0, stream>>>(hp, row_ptr, csr_src, dinv, b3, h16, 0);

  // pool + fc
  pool_kernel<<<512, 256, 0, stream>>>(h16, batch, pool, cnt);
  fc_kernel<<<NUM_GRAPHS, 64, 0, stream>>>(pool, cnt, Wfc, bfc, out);
}